// Round 10
// baseline (341.034 us; speedup 1.0000x reference)
//
#include <hip/hip_runtime.h>
#include <hip/hip_bf16.h>
#include <cstdint>

#define DEV static __device__ __forceinline__

typedef __attribute__((ext_vector_type(8))) short short8_;
typedef __attribute__((ext_vector_type(4))) float float4_;
typedef __attribute__((ext_vector_type(4))) float f4v;
typedef __attribute__((ext_vector_type(4))) unsigned short u16x4;
typedef __attribute__((ext_vector_type(2))) uint32_t u32x2;
typedef unsigned short u16;

constexpr int Bb   = 2;
constexpr int Ls   = 2048;
constexpr int DIMc = 1024;
constexpr int Hh   = 16;
constexpr int Dd   = 64;
constexpr int BL   = Bb * Ls;   // 4096
constexpr int HD   = Hh * Dd;   // 1024

DEV u16 f2bf(float f) {
  union { float f; uint32_t u; } v; v.f = f;
  return (u16)((v.u + 0x7fffu + ((v.u >> 16) & 1u)) >> 16);
}

DEV float4_ mfma16(short8_ a, short8_ b, float4_ c) {
  return __builtin_amdgcn_mfma_f32_16x16x32_bf16(a, b, c, 0, 0, 0);
}

DEV void gload_lds16(const void* g, void* l) {
  __builtin_amdgcn_global_load_lds(
      (const __attribute__((address_space(1))) void*)g,
      (__attribute__((address_space(3))) void*)l, 16, 0, 0);
}

// ---------------- fused prep: casts + weight transposes + gate dots ----------------
__global__ void k_prep(const float* __restrict__ query, const float* __restrict__ keys,
                       const float* __restrict__ values, u16* __restrict__ qx,
                       u16* __restrict__ kx, u16* __restrict__ vx,
                       const float* __restrict__ Wq, const float* __restrict__ Wk,
                       const float* __restrict__ Wv, const float* __restrict__ Wp,
                       u16* __restrict__ WqT, u16* __restrict__ WkT,
                       u16* __restrict__ WvT, u16* __restrict__ WpT,
                       const float* __restrict__ Wt, const float* __restrict__ bt,
                       const float* __restrict__ Wi, const float* __restrict__ bi,
                       const float* __restrict__ focus,
                       float* __restrict__ ts, float* __restrict__ is_,
                       float* __restrict__ rs) {
  __shared__ float t[64][65];
  const int bid = blockIdx.x, tid = threadIdx.x;
  if (bid < 12288) {
    int z = bid >> 12;
    const float* s = (z == 0) ? query : (z == 1) ? keys : values;
    u16* d = (z == 0) ? qx : (z == 1) ? kx : vx;
    int i = (bid & 4095) * 256 + tid;
    f4v v = ((const f4v*)s)[i];
    u16x4 o = { f2bf(v[0]), f2bf(v[1]), f2bf(v[2]), f2bf(v[3]) };
    ((u16x4*)d)[i] = o;
  } else if (bid < 13312) {
    int r2 = bid - 12288;
    int z = r2 >> 8, rem = r2 & 255;
    const float* W = (z == 0) ? Wq : (z == 1) ? Wk : (z == 2) ? Wv : Wp;
    u16* WT = (z == 0) ? WqT : (z == 1) ? WkT : (z == 2) ? WvT : WpT;
    int n0 = (rem >> 4) * 64, k0 = (rem & 15) * 64;
    int tx = tid & 63, tg = tid >> 6;
#pragma unroll
    for (int i = 0; i < 16; ++i) {
      int r = tg * 16 + i;
      t[r][tx] = W[(size_t)(k0 + r) * HD + n0 + tx];
    }
    __syncthreads();
#pragma unroll
    for (int i = 0; i < 16; ++i) {
      int r = tg * 16 + i;
      WT[(size_t)(n0 + r) * DIMc + k0 + tx] = f2bf(t[tx][r]);
    }
  } else {
    int wv = tid >> 6, ln = tid & 63;
    int row = (bid - 13312) * 4 + wv;
    int b = row >> 11;
    const float* kr = keys + (size_t)row * DIMc;
    const float* fr = focus + (size_t)b * DIMc;
    float st = 0.f, si = 0.f, sr = 0.f;
    for (int j = ln; j < DIMc; j += 64) {
      float kv = kr[j];
      st += kv * Wt[j]; si += kv * Wi[j]; sr += kv * fr[j];
    }
#pragma unroll
    for (int m = 1; m < 64; m <<= 1) {
      st += __shfl_xor(st, m); si += __shfl_xor(si, m); sr += __shfl_xor(sr, m);
    }
    if (ln == 0) { ts[row] = st + bt[0]; is_[row] = si + bi[0]; rs[row] = sr; }
  }
}

// ------- gate softmaxes + combined (pre-scaled by 1/8 for QK) -------
__global__ void k_combined(const float* __restrict__ ts, const float* __restrict__ is_,
                           const float* __restrict__ rs, const float* __restrict__ tw,
                           const float* __restrict__ iw, float* __restrict__ comb) {
  int b = blockIdx.x, t = threadIdx.x;
  __shared__ float red[3][4];
  float lt[8], li[8], lr[8];
  float m3[3] = {-1e30f, -1e30f, -1e30f};
#pragma unroll
  for (int i = 0; i < 8; ++i) {
    int gi = b * Ls + i * 256 + t;
    lt[i] = ts[gi] * tw[gi];
    li[i] = is_[gi] * iw[gi];
    lr[i] = rs[gi];
    m3[0] = fmaxf(m3[0], lt[i]); m3[1] = fmaxf(m3[1], li[i]); m3[2] = fmaxf(m3[2], lr[i]);
  }
#pragma unroll
  for (int q = 0; q < 3; ++q) {
    float v = m3[q];
#pragma unroll
    for (int m = 32; m; m >>= 1) v = fmaxf(v, __shfl_xor(v, m));
    if ((t & 63) == 0) red[q][t >> 6] = v;
  }
  __syncthreads();
#pragma unroll
  for (int q = 0; q < 3; ++q)
    m3[q] = fmaxf(fmaxf(red[q][0], red[q][1]), fmaxf(red[q][2], red[q][3]));
  __syncthreads();
  float s3[3] = {0.f, 0.f, 0.f};
#pragma unroll
  for (int i = 0; i < 8; ++i) {
    lt[i] = __expf(lt[i] - m3[0]); s3[0] += lt[i];
    li[i] = __expf(li[i] - m3[1]); s3[1] += li[i];
    lr[i] = __expf(lr[i] - m3[2]); s3[2] += lr[i];
  }
#pragma unroll
  for (int q = 0; q < 3; ++q) {
    float v = s3[q];
#pragma unroll
    for (int m = 32; m; m >>= 1) v += __shfl_xor(v, m);
    if ((t & 63) == 0) red[q][t >> 6] = v;
  }
  __syncthreads();
#pragma unroll
  for (int q = 0; q < 3; ++q) s3[q] = red[q][0] + red[q][1] + red[q][2] + red[q][3];
  float rt = 1.f / s3[0], ri = 1.f / s3[1], rr = 1.f / s3[2];
  const float scl = (1.f / 3.f) * 0.125f;   // /3 combine, /8 = 1/sqrt(D)
#pragma unroll
  for (int i = 0; i < 8; ++i) {
    int gi = b * Ls + i * 256 + t;
    comb[gi] = (lt[i] * rt + li[i] * ri + lr[i] * rr) * scl;
  }
}

// -------- fused QKV GEMM: 768 blocks, 3/CU -> fully co-resident --------
__launch_bounds__(256, 3)
__global__ void k_gemm_qkv(const u16* __restrict__ qx, const u16* __restrict__ kx,
                           const u16* __restrict__ vx, const u16* __restrict__ WqT,
                           const u16* __restrict__ WkT, const u16* __restrict__ WvT,
                           const float* __restrict__ bq, const float* __restrict__ bk,
                           const float* __restrict__ bv, u16* __restrict__ q_bh,
                           u16* __restrict__ k_bh, u16* __restrict__ vT) {
  __shared__ __align__(16) u16 As[128 * 32];
  __shared__ __align__(16) u16 Bs[128 * 32];
  const int z = blockIdx.z;
  const u16* A  = (z == 0) ? qx : (z == 1) ? kx : vx;
  const u16* BT = (z == 0) ? WqT : (z == 1) ? WkT : WvT;
  const float* bias = (z == 0) ? bq : (z == 1) ? bk : bv;
  const int tid = threadIdx.x, wv = tid >> 6, ln = tid & 63;
  const int g = ln >> 4, c = ln & 15;
  const int m0 = blockIdx.x * 128, n0 = blockIdx.y * 128;
  const int wm = wv >> 1, wn = wv & 1;
  const float4_ z4 = {0.f, 0.f, 0.f, 0.f};
  float4_ acc[4][4];
#pragma unroll
  for (int i = 0; i < 4; ++i)
#pragma unroll
    for (int j = 0; j < 4; ++j) acc[i][j] = z4;
  const int lrow = ln >> 2, lcol = (ln & 3) * 8;
  for (int k0 = 0; k0 < 1024; k0 += 32) {
#pragma unroll
    for (int s = 0; s < 2; ++s) {
      int r0 = wv * 32 + s * 16;
      gload_lds16(A  + (size_t)(m0 + r0 + lrow) * 1024 + k0 + lcol, &As[r0 * 32]);
      gload_lds16(BT + (size_t)(n0 + r0 + lrow) * 1024 + k0 + lcol, &Bs[r0 * 32]);
    }
    __syncthreads();
    short8_ af[4], bfr[4];
#pragma unroll
    for (int mt = 0; mt < 4; ++mt)
      af[mt] = *(const short8_*)&As[(wm * 64 + mt * 16 + c) * 32 + g * 8];
#pragma unroll
    for (int nt = 0; nt < 4; ++nt)
      bfr[nt] = *(const short8_*)&Bs[(wn * 64 + nt * 16 + c) * 32 + g * 8];
#pragma unroll
    for (int mt = 0; mt < 4; ++mt)
#pragma unroll
      for (int nt = 0; nt < 4; ++nt)
        acc[mt][nt] = mfma16(af[mt], bfr[nt], acc[mt][nt]);
    __syncthreads();
  }
  if (z < 2) {  // q_bh / k_bh : bf16 [B,H,L,D]
    u16* Q = (z == 0) ? q_bh : k_bh;
#pragma unroll
    for (int mt = 0; mt < 4; ++mt)
#pragma unroll
      for (int nt = 0; nt < 4; ++nt) {
        int n = n0 + wn * 64 + nt * 16 + c;
        float bv_ = bias[n];
        int h = n >> 6, d = n & 63;
#pragma unroll
        for (int r = 0; r < 4; ++r) {
          int m = m0 + wm * 64 + mt * 16 + g * 4 + r;
          int b = m >> 11, l = m & 2047;
          Q[((size_t)((b * Hh + h) * Ls + l)) * Dd + d] = f2bf(acc[mt][nt][r] + bv_);
        }
      }
  } else {      // vT : bf16 [B,H,D,L]
#pragma unroll
    for (int mt = 0; mt < 4; ++mt)
#pragma unroll
      for (int nt = 0; nt < 4; ++nt) {
        int n = n0 + wn * 64 + nt * 16 + c;
        float bv_ = bias[n];
        int h = n >> 6, d = n & 63;
        int mrow = m0 + wm * 64 + mt * 16 + g * 4;
        int b = mrow >> 11, l = mrow & 2047;
        u16x4 o = { f2bf(acc[mt][nt][0] + bv_), f2bf(acc[mt][nt][1] + bv_),
                    f2bf(acc[mt][nt][2] + bv_), f2bf(acc[mt][nt][3] + bv_) };
        *(u16x4*)&vT[((size_t)((b * Hh + h) * Dd + d)) * Ls + l] = o;
      }
  }
}

// ---------------- attention v8: R5 pass 1 + barrier-free pass 2 --------------
// Pass 2 reads K fragments straight from global (L2-hot after pass 1; wave
// covers contiguous 2KB per fragment pair) -> no LDS, no __syncthreads, no
// per-tile vmcnt(0) drain of the 16 outstanding float4 weight stores.
__launch_bounds__(256, 4)
__global__ void k_attn8(const u16* __restrict__ q_bh, const u16* __restrict__ k_bh,
                        const u16* __restrict__ vT, const float* __restrict__ comb_g,
                        float* __restrict__ wout, u16* __restrict__ ctx) {
  __shared__ __align__(16) u16 Kt[2][64][64];
  __shared__ __align__(16) u16 Vt[2][64][64];      // aliased for ctx staging after pass 1
  __shared__ __align__(16) uint32_t Ew[4][16][32]; // e packed 2xbf16, XOR-chunk swizzled

  const int bid = blockIdx.x;
  const int logical = (bid & 7) * 128 + (bid >> 3);   // bijective: 4 bh per XCD
  const int bh = logical >> 5, qb = logical & 31;
  const int b = bh >> 4, h = bh & 15;
  const int l0 = qb * 64;
  const int w = threadIdx.x >> 6, ln = threadIdx.x & 63;
  const int g = ln >> 4, c = ln & 15;
  const int srow = ln >> 3, x8 = ln & 7;
  const float4_ z4 = {0.f, 0.f, 0.f, 0.f};

  const u16* kbh = k_bh + (size_t)bh * Ls * Dd;
  const u16* vbh = vT + (size_t)bh * Dd * Ls;
  const float* kcomb = comb_g + (size_t)b * Ls;

  const u16* qp = q_bh + ((size_t)bh * Ls + l0 + w * 16) * Dd;
  short8_ aq0 = *(const short8_*)&qp[c * Dd + g * 8];
  short8_ aq1 = *(const short8_*)&qp[c * Dd + 32 + g * 8];

  auto stageK = [&](int buf, int kb) {
#pragma unroll
    for (int i = 0; i < 2; ++i) {
      int rr = w * 16 + i * 8 + srow;
      int sc = (x8 ^ (rr & 7)) * 8;
      gload_lds16(kbh + (size_t)(kb + rr) * Dd + sc, &Kt[buf][w * 16 + i * 8][0]);
    }
  };
  auto stageV = [&](int buf, int kb) {
#pragma unroll
    for (int i = 0; i < 2; ++i) {
      int rr = w * 16 + i * 8 + srow;
      int sc = (x8 ^ (rr & 7)) * 8;
      gload_lds16(vbh + (size_t)rr * Ls + kb + sc, &Vt[buf][w * 16 + i * 8][0]);
    }
  };

  float4_ accO[4];
#pragma unroll
  for (int dt = 0; dt < 4; ++dt) accO[dt] = z4;
  float rs_loc = 0.f;

  stageK(0, 0); stageV(0, 0);
  __syncthreads();

  int buf = 0;
  // ---------------- pass 1 (identical to R5) ----------------
  for (int t = 0; t < 32; ++t) {
    if (t < 31) { stageK(buf ^ 1, (t + 1) * 64); stageV(buf ^ 1, (t + 1) * 64); }
    const int kb = t * 64;
#pragma unroll
    for (int s = 0; s < 4; ++s) {
      int rowK = s * 16 + c;
      short8_ bk0 = *(const short8_*)&Kt[buf][rowK][((g    ) ^ (c & 7)) * 8];
      short8_ bk1 = *(const short8_*)&Kt[buf][rowK][((4 + g) ^ (c & 7)) * 8];
      // S^T: lane (c,g) -> q-row c, keys kb + s*16 + g*4 + r
      float4_ st = mfma16(bk0, aq0, z4);
      st = mfma16(bk1, aq1, st);
      float4_ cc4 = *(const float4_*)&kcomb[kb + s * 16 + g * 4];
      float e0 = __expf(st[0] * cc4[0]), e1 = __expf(st[1] * cc4[1]);
      float e2 = __expf(st[2] * cc4[2]), e3 = __expf(st[3] * cc4[3]);
      rs_loc += (e0 + e1) + (e2 + e3);
      u32x2 pk = { ((uint32_t)f2bf(e1) << 16) | f2bf(e0),
                   ((uint32_t)f2bf(e3) << 16) | f2bf(e2) };
      int chunk = (s * 2 + (g >> 1)) ^ (c & 7);
      *(u32x2*)&Ew[w][c][chunk * 4 + (g & 1) * 2] = pk;
    }
#pragma unroll
    for (int hf = 0; hf < 2; ++hf) {
      short8_ ea = *(const short8_*)&Ew[w][c][((hf * 4 + g) ^ (c & 7)) * 4];
#pragma unroll
      for (int dt = 0; dt < 4; ++dt) {
        short8_ bv = *(const short8_*)&Vt[buf][dt * 16 + c][((hf * 4 + g) ^ (c & 7)) * 8];
        accO[dt] = mfma16(ea, bv, accO[dt]);
      }
    }
    __syncthreads();
    buf ^= 1;
  }

  // rowsum reduce across the 4 g-groups; every lane then holds inv for q-row c
  rs_loc += __shfl_xor(rs_loc, 16);
  rs_loc += __shfl_xor(rs_loc, 32);
  float inv = 1.0f / rs_loc;          // lives in a register through pass 2
  float invrow[4];
#pragma unroll
  for (int r = 0; r < 4; ++r) invrow[r] = __shfl(inv, g * 4 + r);

  // ctx: normalize, stage in dead Vt, coalesced bf16 dump
  u16* out_lds = &Vt[0][0][0] + w * 1152;   // 16 rows x 72 per wave
#pragma unroll
  for (int dt = 0; dt < 4; ++dt)
#pragma unroll
    for (int r = 0; r < 4; ++r)
      out_lds[(g * 4 + r) * 72 + dt * 16 + c] = f2bf(accO[dt][r] * invrow[r]);
  {
    int rr2 = ln >> 2, sg = ln & 3;
    short8_ d0 = *(const short8_*)&out_lds[rr2 * 72 + sg * 16];
    short8_ d1 = *(const short8_*)&out_lds[rr2 * 72 + sg * 16 + 8];
    u16* cp = ctx + ((size_t)(b * Ls + l0 + w * 16 + rr2)) * HD + h * Dd + sg * 16;
    *(short8_*)cp = d0;
    *(short8_*)(cp + 8) = d1;
  }

  // -------- pass 2: barrier-free, K direct from global (L2-hot) --------
  float* wb = wout + ((size_t)bh * Ls + l0 + w * 16) * Ls;
  for (int t = 0; t < 32; ++t) {
    const int kb = t * 64;
#pragma unroll
    for (int s = 0; s < 4; ++s) {
      const u16* kr = kbh + (size_t)(kb + s * 16 + c) * Dd;
      short8_ bk0 = *(const short8_*)&kr[g * 8];
      short8_ bk1 = *(const short8_*)&kr[32 + g * 8];
      float4_ st = mfma16(bk0, aq0, z4);
      st = mfma16(bk1, aq1, st);
      float4_ cc4 = *(const float4_*)&kcomb[kb + s * 16 + g * 4];
      float4_ o;
#pragma unroll
      for (int r = 0; r < 4; ++r) o[r] = __expf(st[r] * cc4[r]) * inv;
      *(float4_*)&wb[(size_t)c * Ls + kb + s * 16 + g * 4] = o;
    }
  }
}

// -------- output GEMM: 64x128 tiles -> 512 WGs (2/CU) --------
__launch_bounds__(256, 4)
__global__ void k_gemmO(const u16* __restrict__ A, const u16* __restrict__ BT,
                        const float* __restrict__ bias, float* __restrict__ O) {
  __shared__ __align__(16) u16 As[64 * 32];
  __shared__ __align__(16) u16 Bs[128 * 32];
  const int tid = threadIdx.x, wv = tid >> 6, ln = tid & 63;
  const int g = ln >> 4, c = ln & 15;
  const int m0 = blockIdx.x * 64, n0 = blockIdx.y * 128;
  const int wm = wv >> 1, wn = wv & 1;
  const float4_ z4 = {0.f, 0.f, 0.f, 0.f};
  float4_ acc[2][4];
#pragma unroll
  for (int i = 0; i < 2; ++i)
#pragma unroll
    for (int j = 0; j < 4; ++j) acc[i][j] = z4;
  const int lrow = ln >> 2, lcol = (ln & 3) * 8;
  for (int k0 = 0; k0 < 1024; k0 += 32) {
    gload_lds16(A + (size_t)(m0 + wv * 16 + lrow) * 1024 + k0 + lcol, &As[(wv * 16) * 32]);
#pragma unroll
    for (int s = 0; s < 2; ++s) {
      int r0 = wv * 32 + s * 16;
      gload_lds16(BT + (size_t)(n0 + r0 + lrow) * 1024 + k0 + lcol, &Bs[r0 * 32]);
    }
    __syncthreads();
    short8_ af[2], bfr[4];
#pragma unroll
    for (int mt = 0; mt < 2; ++mt)
      af[mt] = *(const short8_*)&As[(wm * 32 + mt * 16 + c) * 32 + g * 8];
#pragma unroll
    for (int nt = 0; nt < 4; ++nt)
      bfr[nt] = *(const short8_*)&Bs[(wn * 64 + nt * 16 + c) * 32 + g * 8];
#pragma unroll
    for (int mt = 0; mt < 2; ++mt)
#pragma unroll
      for (int nt = 0; nt < 4; ++nt)
        acc[mt][nt] = mfma16(af[mt], bfr[nt], acc[mt][nt]);
    __syncthreads();
  }
#pragma unroll
  for (int mt = 0; mt < 2; ++mt)
#pragma unroll
    for (int nt = 0; nt < 4; ++nt) {
      int n = n0 + wn * 64 + nt * 16 + c;
      float bv_ = bias[n];
#pragma unroll
      for (int r = 0; r < 4; ++r) {
        int m = m0 + wm * 32 + mt * 16 + g * 4 + r;
        O[(size_t)m * HD + n] = acc[mt][nt][r] + bv_;
      }
    }
}

// ---------------- launch ----------------
extern "C" void kernel_launch(void* const* d_in, const int* in_sizes, int n_in,
                              void* d_out, int out_size, void* d_ws, size_t ws_size,
                              hipStream_t stream) {
  (void)in_sizes; (void)n_in; (void)out_size; (void)ws_size;
  const float* query = (const float*)d_in[0];
  const float* keys  = (const float*)d_in[1];
  const float* values= (const float*)d_in[2];
  const float* focus = (const float*)d_in[3];
  const float* twg   = (const float*)d_in[4];
  const float* iwg   = (const float*)d_in[5];
  const float* Wq = (const float*)d_in[6];  const float* bq = (const float*)d_in[7];
  const float* Wk = (const float*)d_in[8];  const float* bk = (const float*)d_in[9];
  const float* Wv = (const float*)d_in[10]; const float* bv = (const float*)d_in[11];
  const float* Wp = (const float*)d_in[12]; const float* bp = (const float*)d_in[13];
  const float* Wt = (const float*)d_in[14]; const float* bt = (const float*)d_in[15];
  const float* Wi = (const float*)d_in[16]; const float* bi = (const float*)d_in[17];

  char* ws = (char*)d_ws;
  size_t off = 0;
  auto alloc = [&](size_t bytes) -> char* {
    char* p = ws + off; off += (bytes + 255) & ~(size_t)255; return p;
  };
  const size_t NTOK = (size_t)BL * DIMc;          // 4,194,304
  u16* qx   = (u16*)alloc(NTOK * 2);
  u16* kx   = (u16*)alloc(NTOK * 2);
  u16* vx   = (u16*)alloc(NTOK * 2);
  u16* WqT  = (u16*)alloc((size_t)DIMc * HD * 2);
  u16* WkT  = (u16*)alloc((size_t)DIMc * HD * 2);
  u16* WvT  = (u16*)alloc((size_t)DIMc * HD * 2);
  u16* WpT  = (u16*)alloc((size_t)DIMc * HD * 2);
  u16* q_bh = (u16*)alloc(NTOK * 2);
  u16* k_bh = (u16*)alloc(NTOK * 2);
  u16* vTb  = (u16*)alloc(NTOK * 2);
  u16* ctx  = (u16*)alloc(NTOK * 2);
  float* ts   = (float*)alloc((size_t)BL * 4);
  float* is_  = (float*)alloc((size_t)BL * 4);
  float* rs   = (float*)alloc((size_t)BL * 4);
  float* comb = (float*)alloc((size_t)BL * 4);

  float* out_f = (float*)d_out;
  float* w_out = out_f + (size_t)BL * HD;   // weights region

  k_prep<<<14336, 256, 0, stream>>>(query, keys, values, qx, kx, vx,
                                    Wq, Wk, Wv, Wp, WqT, WkT, WvT, WpT,
                                    Wt, bt, Wi, bi, focus, ts, is_, rs);
  k_combined<<<2, 256, 0, stream>>>(ts, is_, rs, twg, iwg, comb);
  dim3 gq(32, 8, 3);
  k_gemm_qkv<<<gq, 256, 0, stream>>>(qx, kx, vx, WqT, WkT, WvT, bq, bk, bv,
                                     q_bh, k_bh, vTb);
  k_attn8<<<1024, 256, 0, stream>>>(q_bh, k_bh, vTb, comb, w_out, ctx);
  dim3 go(64, 8);
  k_gemmO<<<go, 256, 0, stream>>>(ctx, WpT, bp, out_f);
}

// Round 11
// 280.818 us; speedup vs baseline: 1.2144x; 1.2144x over previous
//
#include <hip/hip_runtime.h>
#include <hip/hip_bf16.h>
#include <cstdint>

#define DEV static __device__ __forceinline__

typedef __attribute__((ext_vector_type(8))) short short8_;
typedef __attribute__((ext_vector_type(4))) float float4_;
typedef __attribute__((ext_vector_type(4))) float f4v;
typedef __attribute__((ext_vector_type(4))) unsigned short u16x4;
typedef __attribute__((ext_vector_type(2))) uint32_t u32x2;
typedef unsigned short u16;

constexpr int Bb   = 2;
constexpr int Ls   = 2048;
constexpr int DIMc = 1024;
constexpr int Hh   = 16;
constexpr int Dd   = 64;
constexpr int BL   = Bb * Ls;   // 4096
constexpr int HD   = Hh * Dd;   // 1024

DEV u16 f2bf(float f) {
  union { float f; uint32_t u; } v; v.f = f;
  return (u16)((v.u + 0x7fffu + ((v.u >> 16) & 1u)) >> 16);
}

DEV float4_ mfma16(short8_ a, short8_ b, float4_ c) {
  return __builtin_amdgcn_mfma_f32_16x16x32_bf16(a, b, c, 0, 0, 0);
}

DEV void gload_lds16(const void* g, void* l) {
  __builtin_amdgcn_global_load_lds(
      (const __attribute__((address_space(1))) void*)g,
      (__attribute__((address_space(3))) void*)l, 16, 0, 0);
}

// ---------------- fused prep: casts + weight transposes + gate dots ----------------
__global__ void k_prep(const float* __restrict__ query, const float* __restrict__ keys,
                       const float* __restrict__ values, u16* __restrict__ qx,
                       u16* __restrict__ kx, u16* __restrict__ vx,
                       const float* __restrict__ Wq, const float* __restrict__ Wk,
                       const float* __restrict__ Wv, const float* __restrict__ Wp,
                       u16* __restrict__ WqT, u16* __restrict__ WkT,
                       u16* __restrict__ WvT, u16* __restrict__ WpT,
                       const float* __restrict__ Wt, const float* __restrict__ bt,
                       const float* __restrict__ Wi, const float* __restrict__ bi,
                       const float* __restrict__ focus,
                       float* __restrict__ ts, float* __restrict__ is_,
                       float* __restrict__ rs) {
  __shared__ float t[64][65];
  const int bid = blockIdx.x, tid = threadIdx.x;
  if (bid < 12288) {
    int z = bid >> 12;
    const float* s = (z == 0) ? query : (z == 1) ? keys : values;
    u16* d = (z == 0) ? qx : (z == 1) ? kx : vx;
    int i = (bid & 4095) * 256 + tid;
    f4v v = ((const f4v*)s)[i];
    u16x4 o = { f2bf(v[0]), f2bf(v[1]), f2bf(v[2]), f2bf(v[3]) };
    ((u16x4*)d)[i] = o;
  } else if (bid < 13312) {
    int r2 = bid - 12288;
    int z = r2 >> 8, rem = r2 & 255;
    const float* W = (z == 0) ? Wq : (z == 1) ? Wk : (z == 2) ? Wv : Wp;
    u16* WT = (z == 0) ? WqT : (z == 1) ? WkT : (z == 2) ? WvT : WpT;
    int n0 = (rem >> 4) * 64, k0 = (rem & 15) * 64;
    int tx = tid & 63, tg = tid >> 6;
#pragma unroll
    for (int i = 0; i < 16; ++i) {
      int r = tg * 16 + i;
      t[r][tx] = W[(size_t)(k0 + r) * HD + n0 + tx];
    }
    __syncthreads();
#pragma unroll
    for (int i = 0; i < 16; ++i) {
      int r = tg * 16 + i;
      WT[(size_t)(n0 + r) * DIMc + k0 + tx] = f2bf(t[tx][r]);
    }
  } else {
    int wv = tid >> 6, ln = tid & 63;
    int row = (bid - 13312) * 4 + wv;
    int b = row >> 11;
    const float* kr = keys + (size_t)row * DIMc;
    const float* fr = focus + (size_t)b * DIMc;
    float st = 0.f, si = 0.f, sr = 0.f;
    for (int j = ln; j < DIMc; j += 64) {
      float kv = kr[j];
      st += kv * Wt[j]; si += kv * Wi[j]; sr += kv * fr[j];
    }
#pragma unroll
    for (int m = 1; m < 64; m <<= 1) {
      st += __shfl_xor(st, m); si += __shfl_xor(si, m); sr += __shfl_xor(sr, m);
    }
    if (ln == 0) { ts[row] = st + bt[0]; is_[row] = si + bi[0]; rs[row] = sr; }
  }
}

// ------- gate softmaxes + combined (pre-scaled by 1/8 for QK) -------
__global__ void k_combined(const float* __restrict__ ts, const float* __restrict__ is_,
                           const float* __restrict__ rs, const float* __restrict__ tw,
                           const float* __restrict__ iw, float* __restrict__ comb) {
  int b = blockIdx.x, t = threadIdx.x;
  __shared__ float red[3][4];
  float lt[8], li[8], lr[8];
  float m3[3] = {-1e30f, -1e30f, -1e30f};
#pragma unroll
  for (int i = 0; i < 8; ++i) {
    int gi = b * Ls + i * 256 + t;
    lt[i] = ts[gi] * tw[gi];
    li[i] = is_[gi] * iw[gi];
    lr[i] = rs[gi];
    m3[0] = fmaxf(m3[0], lt[i]); m3[1] = fmaxf(m3[1], li[i]); m3[2] = fmaxf(m3[2], lr[i]);
  }
#pragma unroll
  for (int q = 0; q < 3; ++q) {
    float v = m3[q];
#pragma unroll
    for (int m = 32; m; m >>= 1) v = fmaxf(v, __shfl_xor(v, m));
    if ((t & 63) == 0) red[q][t >> 6] = v;
  }
  __syncthreads();
#pragma unroll
  for (int q = 0; q < 3; ++q)
    m3[q] = fmaxf(fmaxf(red[q][0], red[q][1]), fmaxf(red[q][2], red[q][3]));
  __syncthreads();
  float s3[3] = {0.f, 0.f, 0.f};
#pragma unroll
  for (int i = 0; i < 8; ++i) {
    lt[i] = __expf(lt[i] - m3[0]); s3[0] += lt[i];
    li[i] = __expf(li[i] - m3[1]); s3[1] += li[i];
    lr[i] = __expf(lr[i] - m3[2]); s3[2] += lr[i];
  }
#pragma unroll
  for (int q = 0; q < 3; ++q) {
    float v = s3[q];
#pragma unroll
    for (int m = 32; m; m >>= 1) v += __shfl_xor(v, m);
    if ((t & 63) == 0) red[q][t >> 6] = v;
  }
  __syncthreads();
#pragma unroll
  for (int q = 0; q < 3; ++q) s3[q] = red[q][0] + red[q][1] + red[q][2] + red[q][3];
  float rt = 1.f / s3[0], ri = 1.f / s3[1], rr = 1.f / s3[2];
  const float scl = (1.f / 3.f) * 0.125f;   // /3 combine, /8 = 1/sqrt(D)
#pragma unroll
  for (int i = 0; i < 8; ++i) {
    int gi = b * Ls + i * 256 + t;
    comb[gi] = (lt[i] * rt + li[i] * ri + lr[i] * rr) * scl;
  }
}

// -------- fused QKV GEMM: 768 blocks, 3/CU -> fully co-resident --------
__launch_bounds__(256, 3)
__global__ void k_gemm_qkv(const u16* __restrict__ qx, const u16* __restrict__ kx,
                           const u16* __restrict__ vx, const u16* __restrict__ WqT,
                           const u16* __restrict__ WkT, const u16* __restrict__ WvT,
                           const float* __restrict__ bq, const float* __restrict__ bk,
                           const float* __restrict__ bv, u16* __restrict__ q_bh,
                           u16* __restrict__ k_bh, u16* __restrict__ vT) {
  __shared__ __align__(16) u16 As[128 * 32];
  __shared__ __align__(16) u16 Bs[128 * 32];
  const int z = blockIdx.z;
  const u16* A  = (z == 0) ? qx : (z == 1) ? kx : vx;
  const u16* BT = (z == 0) ? WqT : (z == 1) ? WkT : WvT;
  const float* bias = (z == 0) ? bq : (z == 1) ? bk : bv;
  const int tid = threadIdx.x, wv = tid >> 6, ln = tid & 63;
  const int g = ln >> 4, c = ln & 15;
  const int m0 = blockIdx.x * 128, n0 = blockIdx.y * 128;
  const int wm = wv >> 1, wn = wv & 1;
  const float4_ z4 = {0.f, 0.f, 0.f, 0.f};
  float4_ acc[4][4];
#pragma unroll
  for (int i = 0; i < 4; ++i)
#pragma unroll
    for (int j = 0; j < 4; ++j) acc[i][j] = z4;
  const int lrow = ln >> 2, lcol = (ln & 3) * 8;
  for (int k0 = 0; k0 < 1024; k0 += 32) {
#pragma unroll
    for (int s = 0; s < 2; ++s) {
      int r0 = wv * 32 + s * 16;
      gload_lds16(A  + (size_t)(m0 + r0 + lrow) * 1024 + k0 + lcol, &As[r0 * 32]);
      gload_lds16(BT + (size_t)(n0 + r0 + lrow) * 1024 + k0 + lcol, &Bs[r0 * 32]);
    }
    __syncthreads();
    short8_ af[4], bfr[4];
#pragma unroll
    for (int mt = 0; mt < 4; ++mt)
      af[mt] = *(const short8_*)&As[(wm * 64 + mt * 16 + c) * 32 + g * 8];
#pragma unroll
    for (int nt = 0; nt < 4; ++nt)
      bfr[nt] = *(const short8_*)&Bs[(wn * 64 + nt * 16 + c) * 32 + g * 8];
#pragma unroll
    for (int mt = 0; mt < 4; ++mt)
#pragma unroll
      for (int nt = 0; nt < 4; ++nt)
        acc[mt][nt] = mfma16(af[mt], bfr[nt], acc[mt][nt]);
    __syncthreads();
  }
  if (z < 2) {  // q_bh / k_bh : bf16 [B,H,L,D]
    u16* Q = (z == 0) ? q_bh : k_bh;
#pragma unroll
    for (int mt = 0; mt < 4; ++mt)
#pragma unroll
      for (int nt = 0; nt < 4; ++nt) {
        int n = n0 + wn * 64 + nt * 16 + c;
        float bv_ = bias[n];
        int h = n >> 6, d = n & 63;
#pragma unroll
        for (int r = 0; r < 4; ++r) {
          int m = m0 + wm * 64 + mt * 16 + g * 4 + r;
          int b = m >> 11, l = m & 2047;
          Q[((size_t)((b * Hh + h) * Ls + l)) * Dd + d] = f2bf(acc[mt][nt][r] + bv_);
        }
      }
  } else {      // vT : bf16 [B,H,D,L]
#pragma unroll
    for (int mt = 0; mt < 4; ++mt)
#pragma unroll
      for (int nt = 0; nt < 4; ++nt) {
        int n = n0 + wn * 64 + nt * 16 + c;
        float bv_ = bias[n];
        int h = n >> 6, d = n & 63;
        int mrow = m0 + wm * 64 + mt * 16 + g * 4;
        int b = mrow >> 11, l = mrow & 2047;
        u16x4 o = { f2bf(acc[mt][nt][0] + bv_), f2bf(acc[mt][nt][1] + bv_),
                    f2bf(acc[mt][nt][2] + bv_), f2bf(acc[mt][nt][3] + bv_) };
        *(u16x4*)&vT[((size_t)((b * Hh + h) * Dd + d)) * Ls + l] = o;
      }
  }
}

// ---------------- attention v9: R5 pass 1 + 4-buffer pass 2 ------------------
// Pass 2 reuses dead Vt as 2 extra K buffers -> 4-deep staging, one barrier
// per 2 tiles (17 vs 32). Each vmcnt(0) drain amortizes 2 tiles of stores.
__launch_bounds__(256, 4)
__global__ void k_attn9(const u16* __restrict__ q_bh, const u16* __restrict__ k_bh,
                        const u16* __restrict__ vT, const float* __restrict__ comb_g,
                        float* __restrict__ wout, u16* __restrict__ ctx) {
  __shared__ __align__(16) u16 Kt[2][64][64];
  __shared__ __align__(16) u16 Vt[2][64][64];      // pass1: V dbuf; pass2: K bufs 2,3
  __shared__ __align__(16) uint32_t Ew[4][16][32]; // e packed 2xbf16, XOR-chunk swizzled

  const int bid = blockIdx.x;
  const int logical = (bid & 7) * 128 + (bid >> 3);   // bijective: 4 bh per XCD
  const int bh = logical >> 5, qb = logical & 31;
  const int b = bh >> 4, h = bh & 15;
  const int l0 = qb * 64;
  const int w = threadIdx.x >> 6, ln = threadIdx.x & 63;
  const int g = ln >> 4, c = ln & 15;
  const int srow = ln >> 3, x8 = ln & 7;
  const float4_ z4 = {0.f, 0.f, 0.f, 0.f};

  const u16* kbh = k_bh + (size_t)bh * Ls * Dd;
  const u16* vbh = vT + (size_t)bh * Dd * Ls;
  const float* kcomb = comb_g + (size_t)b * Ls;

  const u16* qp = q_bh + ((size_t)bh * Ls + l0 + w * 16) * Dd;
  short8_ aq0 = *(const short8_*)&qp[c * Dd + g * 8];
  short8_ aq1 = *(const short8_*)&qp[c * Dd + 32 + g * 8];

  auto stageK = [&](int buf, int kb) {
#pragma unroll
    for (int i = 0; i < 2; ++i) {
      int rr = w * 16 + i * 8 + srow;
      int sc = (x8 ^ (rr & 7)) * 8;
      gload_lds16(kbh + (size_t)(kb + rr) * Dd + sc, &Kt[buf][w * 16 + i * 8][0]);
    }
  };
  auto stageV = [&](int buf, int kb) {
#pragma unroll
    for (int i = 0; i < 2; ++i) {
      int rr = w * 16 + i * 8 + srow;
      int sc = (x8 ^ (rr & 7)) * 8;
      gload_lds16(vbh + (size_t)rr * Ls + kb + sc, &Vt[buf][w * 16 + i * 8][0]);
    }
  };
  // pass-2: stage K into arbitrary LDS base (Kt or Vt regions)
  auto stageKp = [&](u16* base, int kb) {
#pragma unroll
    for (int i = 0; i < 2; ++i) {
      int rr = w * 16 + i * 8 + srow;
      int sc = (x8 ^ (rr & 7)) * 8;
      gload_lds16(kbh + (size_t)(kb + rr) * Dd + sc, base + (w * 16 + i * 8) * 64);
    }
  };

  float4_ accO[4];
#pragma unroll
  for (int dt = 0; dt < 4; ++dt) accO[dt] = z4;
  float rs_loc = 0.f;

  stageK(0, 0); stageV(0, 0);
  __syncthreads();

  int buf = 0;
  // ---------------- pass 1 (identical to R5) ----------------
  for (int t = 0; t < 32; ++t) {
    if (t < 31) { stageK(buf ^ 1, (t + 1) * 64); stageV(buf ^ 1, (t + 1) * 64); }
    const int kb = t * 64;
#pragma unroll
    for (int s = 0; s < 4; ++s) {
      int rowK = s * 16 + c;
      short8_ bk0 = *(const short8_*)&Kt[buf][rowK][((g    ) ^ (c & 7)) * 8];
      short8_ bk1 = *(const short8_*)&Kt[buf][rowK][((4 + g) ^ (c & 7)) * 8];
      // S^T: lane (c,g) -> q-row c, keys kb + s*16 + g*4 + r
      float4_ st = mfma16(bk0, aq0, z4);
      st = mfma16(bk1, aq1, st);
      float4_ cc4 = *(const float4_*)&kcomb[kb + s * 16 + g * 4];
      float e0 = __expf(st[0] * cc4[0]), e1 = __expf(st[1] * cc4[1]);
      float e2 = __expf(st[2] * cc4[2]), e3 = __expf(st[3] * cc4[3]);
      rs_loc += (e0 + e1) + (e2 + e3);
      u32x2 pk = { ((uint32_t)f2bf(e1) << 16) | f2bf(e0),
                   ((uint32_t)f2bf(e3) << 16) | f2bf(e2) };
      int chunk = (s * 2 + (g >> 1)) ^ (c & 7);
      *(u32x2*)&Ew[w][c][chunk * 4 + (g & 1) * 2] = pk;
    }
#pragma unroll
    for (int hf = 0; hf < 2; ++hf) {
      short8_ ea = *(const short8_*)&Ew[w][c][((hf * 4 + g) ^ (c & 7)) * 4];
#pragma unroll
      for (int dt = 0; dt < 4; ++dt) {
        short8_ bv = *(const short8_*)&Vt[buf][dt * 16 + c][((hf * 4 + g) ^ (c & 7)) * 8];
        accO[dt] = mfma16(ea, bv, accO[dt]);
      }
    }
    __syncthreads();
    buf ^= 1;
  }

  // rowsum reduce across the 4 g-groups; every lane then holds inv for q-row c
  rs_loc += __shfl_xor(rs_loc, 16);
  rs_loc += __shfl_xor(rs_loc, 32);
  float inv = 1.0f / rs_loc;          // lives in a register through pass 2
  float invrow[4];
#pragma unroll
  for (int r = 0; r < 4; ++r) invrow[r] = __shfl(inv, g * 4 + r);

  // ctx: normalize, stage in dead Vt, coalesced bf16 dump (before any barrier)
  u16* out_lds = &Vt[0][0][0] + w * 1152;   // 16 rows x 72 per wave
#pragma unroll
  for (int dt = 0; dt < 4; ++dt)
#pragma unroll
    for (int r = 0; r < 4; ++r)
      out_lds[(g * 4 + r) * 72 + dt * 16 + c] = f2bf(accO[dt][r] * invrow[r]);
  {
    int rr2 = ln >> 2, sg = ln & 3;
    short8_ d0 = *(const short8_*)&out_lds[rr2 * 72 + sg * 16];
    short8_ d1 = *(const short8_*)&out_lds[rr2 * 72 + sg * 16 + 8];
    u16* cp = ctx + ((size_t)(b * Ls + l0 + w * 16 + rr2)) * HD + h * Dd + sg * 16;
    *(short8_*)cp = d0;
    *(short8_*)(cp + 8) = d1;
  }

  // -------- pass 2: 4-buffer K staging, barrier per 2 tiles --------
  u16* kb0 = &Kt[0][0][0];
  u16* kb1 = &Kt[1][0][0];
  u16* kb2 = &Vt[0][0][0];
  u16* kb3 = &Vt[1][0][0];
  float* wb = wout + ((size_t)bh * Ls + l0 + w * 16) * Ls;

  auto p2tile = [&](const u16* kbuf, int kb) {
#pragma unroll
    for (int s = 0; s < 4; ++s) {
      int rowK = s * 16 + c;
      short8_ bk0 = *(const short8_*)&kbuf[rowK * 64 + ((g    ) ^ (c & 7)) * 8];
      short8_ bk1 = *(const short8_*)&kbuf[rowK * 64 + ((4 + g) ^ (c & 7)) * 8];
      float4_ st = mfma16(bk0, aq0, z4);
      st = mfma16(bk1, aq1, st);
      float4_ cc4 = *(const float4_*)&kcomb[kb + s * 16 + g * 4];
      float4_ o;
#pragma unroll
      for (int r = 0; r < 4; ++r) o[r] = __expf(st[r] * cc4[r]) * inv;
      *(float4_*)&wb[(size_t)c * Ls + kb + s * 16 + g * 4] = o;
    }
  };

  stageKp(kb0, 0); stageKp(kb1, 64);
  __syncthreads();   // also fences the ctx-dump reads of Vt above
  for (int t = 0; t < 32; t += 4) {
    // phase A: stage t+2,t+3 into kb2/kb3; compute t,t+1 from kb0/kb1
    stageKp(kb2, (t + 2) * 64);
    stageKp(kb3, (t + 3) * 64);
    p2tile(kb0, t * 64);
    p2tile(kb1, (t + 1) * 64);
    __syncthreads();
    // phase B: stage t+4,t+5 into kb0/kb1; compute t+2,t+3 from kb2/kb3
    if (t + 4 < 32) { stageKp(kb0, (t + 4) * 64); stageKp(kb1, (t + 5) * 64); }
    p2tile(kb2, (t + 2) * 64);
    p2tile(kb3, (t + 3) * 64);
    __syncthreads();
  }
}

// -------- output GEMM: 64x128 tiles -> 512 WGs (2/CU) --------
__launch_bounds__(256, 4)
__global__ void k_gemmO(const u16* __restrict__ A, const u16* __restrict__ BT,
                        const float* __restrict__ bias, float* __restrict__ O) {
  __shared__ __align__(16) u16 As[64 * 32];
  __shared__ __align__(16) u16 Bs[128 * 32];
  const int tid = threadIdx.x, wv = tid >> 6, ln = tid & 63;
  const int g = ln >> 4, c = ln & 15;
  const int m0 = blockIdx.x * 64, n0 = blockIdx.y * 128;
  const int wm = wv >> 1, wn = wv & 1;
  const float4_ z4 = {0.f, 0.f, 0.f, 0.f};
  float4_ acc[2][4];
#pragma unroll
  for (int i = 0; i < 2; ++i)
#pragma unroll
    for (int j = 0; j < 4; ++j) acc[i][j] = z4;
  const int lrow = ln >> 2, lcol = (ln & 3) * 8;
  for (int k0 = 0; k0 < 1024; k0 += 32) {
    gload_lds16(A + (size_t)(m0 + wv * 16 + lrow) * 1024 + k0 + lcol, &As[(wv * 16) * 32]);
#pragma unroll
    for (int s = 0; s < 2; ++s) {
      int r0 = wv * 32 + s * 16;
      gload_lds16(BT + (size_t)(n0 + r0 + lrow) * 1024 + k0 + lcol, &Bs[r0 * 32]);
    }
    __syncthreads();
    short8_ af[2], bfr[4];
#pragma unroll
    for (int mt = 0; mt < 2; ++mt)
      af[mt] = *(const short8_*)&As[(wm * 32 + mt * 16 + c) * 32 + g * 8];
#pragma unroll
    for (int nt = 0; nt < 4; ++nt)
      bfr[nt] = *(const short8_*)&Bs[(wn * 64 + nt * 16 + c) * 32 + g * 8];
#pragma unroll
    for (int mt = 0; mt < 2; ++mt)
#pragma unroll
      for (int nt = 0; nt < 4; ++nt)
        acc[mt][nt] = mfma16(af[mt], bfr[nt], acc[mt][nt]);
    __syncthreads();
  }
#pragma unroll
  for (int mt = 0; mt < 2; ++mt)
#pragma unroll
    for (int nt = 0; nt < 4; ++nt) {
      int n = n0 + wn * 64 + nt * 16 + c;
      float bv_ = bias[n];
#pragma unroll
      for (int r = 0; r < 4; ++r) {
        int m = m0 + wm * 32 + mt * 16 + g * 4 + r;
        O[(size_t)m * HD + n] = acc[mt][nt][r] + bv_;
      }
    }
}

// ---------------- launch ----------------
extern "C" void kernel_launch(void* const* d_in, const int* in_sizes, int n_in,
                              void* d_out, int out_size, void* d_ws, size_t ws_size,
                              hipStream_t stream) {
  (void)in_sizes; (void)n_in; (void)out_size; (void)ws_size;
  const float* query = (const float*)d_in[0];
  const float* keys  = (const float*)d_in[1];
  const float* values= (const float*)d_in[2];
  const float* focus = (const float*)d_in[3];
  const float* twg   = (const float*)d_in[4];
  const float* iwg   = (const float*)d_in[5];
  const float* Wq = (const float*)d_in[6];  const float* bq = (const float*)d_in[7];
  const float* Wk = (const float*)d_in[8];  const float* bk = (const float*)d_in[9];
  const float* Wv = (const float*)d_in[10]; const float* bv = (const float*)d_in[11];
  const float* Wp = (const float*)d_in[12]; const float* bp = (const float*)d_in[13];
  const float* Wt = (const float*)d_in[14]; const float* bt = (const float*)d_in[15];
  const float* Wi = (const float*)d_in[16]; const float* bi = (const float*)d_in[17];

  char* ws = (char*)d_ws;
  size_t off = 0;
  auto alloc = [&](size_t bytes) -> char* {
    char* p = ws + off; off += (bytes + 255) & ~(size_t)255; return p;
  };
  const size_t NTOK = (size_t)BL * DIMc;          // 4,194,304
  u16* qx   = (u16*)alloc(NTOK * 2);
  u16* kx   = (u16*)alloc(NTOK * 2);
  u16* vx   = (u16*)alloc(NTOK * 2);
  u16* WqT  = (u16*)alloc((size_t)DIMc * HD * 2);
  u16* WkT  = (u16*)alloc((size_t)DIMc * HD * 2);
  u16* WvT  = (u16*)alloc((size_t)DIMc * HD * 2);
  u16* WpT  = (u16*)alloc((size_t)DIMc * HD * 2);
  u16* q_bh = (u16*)alloc(NTOK * 2);
  u16* k_bh = (u16*)alloc(NTOK * 2);
  u16* vTb  = (u16*)alloc(NTOK * 2);
  u16* ctx  = (u16*)alloc(NTOK * 2);
  float* ts   = (float*)alloc((size_t)BL * 4);
  float* is_  = (float*)alloc((size_t)BL * 4);
  float* rs   = (float*)alloc((size_t)BL * 4);
  float* comb = (float*)alloc((size_t)BL * 4);

  float* out_f = (float*)d_out;
  float* w_out = out_f + (size_t)BL * HD;   // weights region

  k_prep<<<14336, 256, 0, stream>>>(query, keys, values, qx, kx, vx,
                                    Wq, Wk, Wv, Wp, WqT, WkT, WvT, WpT,
                                    Wt, bt, Wi, bi, focus, ts, is_, rs);
  k_combined<<<2, 256, 0, stream>>>(ts, is_, rs, twg, iwg, comb);
  dim3 gq(32, 8, 3);
  k_gemm_qkv<<<gq, 256, 0, stream>>>(qx, kx, vx, WqT, WkT, WvT, bq, bk, bv,
                                     q_bh, k_bh, vTb);
  k_attn9<<<1024, 256, 0, stream>>>(q_bh, k_bh, vTb, comb, w_out, ctx);
  dim3 go(64, 8);
  k_gemmO<<<go, 256, 0, stream>>>(ctx, WpT, bp, out_f);
}